// Round 17
// baseline (449.755 us; speedup 1.0000x reference)
//
#include <hip/hip_runtime.h>

// Attention_11845519803093 — R23: 2 q-tiles per wave in attn (shared K/V/M2 loads).
//   * Each block covers 128 q-rows (tiles A=qt0, B=qt0+64). Per k-tile ONE
//     24-fragment load batch feeds both sub-tiles' S/exp/bins/PV -> loads per
//     MFMA halved; exposed latency amortized 2x. Grid 1920 -> 960.
//   * Sub-tiles processed sequentially (peak VGPR ~210 < 256 cap at (256,2),
//     the allocator's demand-filling regime). LDS 52.5KB -> 2 blocks/CU.
//   * Revert criteria: VGPR<150 (remat) or WRITE_SIZE>>13.8MB (spill) or dur>=433.
//   * GEMMs (BK=64 staged) + init_all = R22 verbatim.
// ws layout: qh | kh | vh | aoh | M2 | xh | wh | pwh

#define BB    16
#define NNq   577
#define DIMM  768
#define NHh   12
#define HD    64
#define MM    9232
#define KT    64
#define NPAD  640
#define NW3   2304

typedef _Float16 h8 __attribute__((ext_vector_type(8)));
typedef _Float16 h4 __attribute__((ext_vector_type(4)));
typedef float    f4 __attribute__((ext_vector_type(4)));

__device__ inline h8 pack8(float4 a, float4 b) {
    h8 r;
    r[0]=(_Float16)a.x; r[1]=(_Float16)a.y; r[2]=(_Float16)a.z; r[3]=(_Float16)a.w;
    r[4]=(_Float16)b.x; r[5]=(_Float16)b.y; r[6]=(_Float16)b.z; r[7]=(_Float16)b.w;
    return r;
}

// ---------------------------------------------------------------- merged init
__global__ void init_all(const float* __restrict__ x, const float* __restrict__ w,
                         const float* __restrict__ pw,
                         _Float16* __restrict__ M2g, _Float16* __restrict__ vh,
                         _Float16* __restrict__ xh, _Float16* __restrict__ wh,
                         _Float16* __restrict__ pwh)
{
    const size_t id = (size_t)blockIdx.x*256 + threadIdx.x;
    if (id < NPAD*64) {
        const int key = (int)id >> 6, bin = (int)id & 63;
        int vb = 255, hb = 255;
        if (key == 0)      { vb = 24; hb = 49; }
        else if (key < NNq){ const int kq = key-1, kv = kq/24; vb = kv; hb = 25 + (kq - kv*24); }
        M2g[bin*NPAD + key] =
            ((key < NNq) && (bin==vb || bin==hb || bin==50)) ? (_Float16)1.f : (_Float16)0.f;
        return;
    }
    const size_t vid = id - NPAD*64;
    if (vid < (size_t)BB*NHh*HD*64) {
        const int head = (int)(vid >> 12);
        const int rem  = (int)vid & 4095;
        const int d    = rem >> 6;
        const int col  = 576 + (rem & 63);
        vh[(size_t)head*(HD*NPAD) + (size_t)d*NPAD + col] = (_Float16)0.f;
        return;
    }
    const size_t cid = vid - (size_t)BB*NHh*HD*64;
    const size_t NX = (size_t)MM*DIMM/4;
    const size_t NW = (size_t)NW3*DIMM/4;
    const size_t NP = (size_t)DIMM*DIMM/4;
    const float4* src; h4* dst; size_t j;
    if (cid < NX)            { src = (const float4*)x;  dst = (h4*)xh;  j = cid; }
    else if (cid < NX+NW)    { src = (const float4*)w;  dst = (h4*)wh;  j = cid - NX; }
    else if (cid < NX+NW+NP) { src = (const float4*)pw; dst = (h4*)pwh; j = cid - NX - NW; }
    else return;
    const float4 v = src[j];
    h4 hh; hh[0]=(_Float16)v.x; hh[1]=(_Float16)v.y; hh[2]=(_Float16)v.z; hh[3]=(_Float16)v.w;
    dst[j] = hh;
}

// ---------------------------------------------------------------- BK=64 staged fp16 GEMM core
template <typename F>
__device__ __forceinline__ void gemm128f2(const _Float16* __restrict__ Ah_g,
                                          const _Float16* __restrict__ Bh_g,
                                          F epi)
{
    __shared__ _Float16 Ah[128][72], Bh[128][72];
    const int t  = threadIdx.x;
    const int wv = t >> 6, lane = t & 63, lo = lane & 15, g = lane >> 4;
    const int gb = g << 3;
    const int wm = (wv >> 1) << 6, wn = (wv & 1) << 6;
    const int bm = blockIdx.y << 7, bn = blockIdx.x << 7;
    f4 acc[4][4] = {};
    const int lr = t >> 1;
    const int lc = (t & 1) << 5;          // 0 or 32
    const int am = bm + lr;
    const bool aok = am < MM;
    const _Float16* arh = Ah_g + (size_t)(aok ? am : 0) * DIMM + lc;
    const _Float16* brh = Bh_g + (size_t)(bn + lr) * DIMM + lc;

    for (int k0 = 0; k0 < DIMM; k0 += 64) {
        h8 a0 = {}, a1 = {}, a2 = {}, a3 = {};
        if (aok) {
            a0 = *(const h8*)(arh + k0);      a1 = *(const h8*)(arh + k0 + 8);
            a2 = *(const h8*)(arh + k0 + 16); a3 = *(const h8*)(arh + k0 + 24);
        }
        const h8 b0 = *(const h8*)(brh + k0),      b1 = *(const h8*)(brh + k0 + 8);
        const h8 b2 = *(const h8*)(brh + k0 + 16), b3 = *(const h8*)(brh + k0 + 24);
        __syncthreads();
        *(h8*)&Ah[lr][lc]    = a0; *(h8*)&Ah[lr][lc+8]  = a1;
        *(h8*)&Ah[lr][lc+16] = a2; *(h8*)&Ah[lr][lc+24] = a3;
        *(h8*)&Bh[lr][lc]    = b0; *(h8*)&Bh[lr][lc+8]  = b1;
        *(h8*)&Bh[lr][lc+16] = b2; *(h8*)&Bh[lr][lc+24] = b3;
        __syncthreads();
        {
            h8 fah[4], fbh[4];
            #pragma unroll
            for (int i = 0; i < 4; ++i) {
                fah[i] = *(const h8*)&Ah[wm + 16*i + lo][gb];
                fbh[i] = *(const h8*)&Bh[wn + 16*i + lo][gb];
            }
            #pragma unroll
            for (int mi = 0; mi < 4; ++mi) {
                #pragma unroll
                for (int ni = 0; ni < 4; ++ni)
                    acc[mi][ni] = __builtin_amdgcn_mfma_f32_16x16x32_f16(fah[mi], fbh[ni], acc[mi][ni], 0, 0, 0);
            }
        }
        {
            h8 fah[4], fbh[4];
            #pragma unroll
            for (int i = 0; i < 4; ++i) {
                fah[i] = *(const h8*)&Ah[wm + 16*i + lo][32 + gb];
                fbh[i] = *(const h8*)&Bh[wn + 16*i + lo][32 + gb];
            }
            #pragma unroll
            for (int mi = 0; mi < 4; ++mi) {
                #pragma unroll
                for (int ni = 0; ni < 4; ++ni)
                    acc[mi][ni] = __builtin_amdgcn_mfma_f32_16x16x32_f16(fah[mi], fbh[ni], acc[mi][ni], 0, 0, 0);
            }
        }
    }
    epi(acc, bm, bn, wm, wn, lo, g);
}

// ---------------------------------------------------------------- QKV GEMM
__global__ __launch_bounds__(256, 3)
void qkv_gemm(const _Float16* __restrict__ xh, const _Float16* __restrict__ wh,
              _Float16* __restrict__ qh, _Float16* __restrict__ kh, _Float16* __restrict__ vh)
{
    gemm128f2(xh, wh, [=](f4 (&acc)[4][4], int bm, int bn, int wm, int wn, int lo, int g) {
        const int three = bn / 768;
        const int cb    = bn - three * 768;
        #pragma unroll
        for (int mi = 0; mi < 4; ++mi) {
            #pragma unroll
            for (int reg = 0; reg < 4; ++reg) {
                const int m = bm + wm + 16*mi + 4*g + reg;
                if (m >= MM) continue;
                const int b_ = m / NNq;
                const int n_ = m - b_ * NNq;
                #pragma unroll
                for (int ni = 0; ni < 4; ++ni) {
                    const int n  = cb + wn + 16*ni + lo;
                    const int hh = n >> 6;
                    const int d  = n & 63;
                    if (three == 0) {
                        // Q scaled 0.125 * log2(e) for the exp2 path
                        qh[((size_t)(b_*NHh + hh)*NPAD + n_)*HD + d] =
                            (_Float16)(acc[mi][ni][reg] * 0.18033688f);
                    } else if (three == 1) {
                        kh[((size_t)(b_*NHh + hh)*NPAD + n_)*HD + d] = (_Float16)acc[mi][ni][reg];
                    } else {
                        vh[((size_t)(b_*NHh + hh)*HD + d)*NPAD + n_] = (_Float16)acc[mi][ni][reg];
                    }
                }
            }
        }
    });
}

// ---------------------------------------------------------------- proj GEMM
__global__ __launch_bounds__(256, 3)
void proj_gemm(const _Float16* __restrict__ aoh, const _Float16* __restrict__ pwh,
               const float* __restrict__ bias, float* __restrict__ out)
{
    gemm128f2(aoh, pwh, [=](f4 (&acc)[4][4], int bm, int bn, int wm, int wn, int lo, int g) {
        #pragma unroll
        for (int ni = 0; ni < 4; ++ni) {
            const int n  = bn + wn + 16*ni + lo;
            const float bb = bias[n];
            #pragma unroll
            for (int mi = 0; mi < 4; ++mi) {
                #pragma unroll
                for (int reg = 0; reg < 4; ++reg) {
                    const int m = bm + wm + 16*mi + 4*g + reg;
                    if (m >= MM) continue;
                    out[(size_t)m*DIMM + n] = acc[mi][ni][reg] + bb;
                }
            }
        }
    });
}

// ---------------------------------------------------------------- fused attention v16 (2 q-tiles/wave)
__global__ __launch_bounds__(256, 2)
void attn_fused(const _Float16* __restrict__ qh,
                const _Float16* __restrict__ kh, const _Float16* __restrict__ vh,
                const float* __restrict__ tkv, const float* __restrict__ tkh,
                const float* __restrict__ tvv, const float* __restrict__ tvh,
                const _Float16* __restrict__ M2g,
                _Float16* __restrict__ aoh)
{
    // LDS 52464 B:
    //   [     0,18432) qrelS fp16 [128][72]
    //   [ 18432,36864) Pt    fp16 [128][72]
    //   [ 36864,52464) TvS   fp32 [60][65]
    //   epilogue: binsS fp32 [128][52] at 0 (26624 B; qrelS + head of Pt dead)
    __shared__ __align__(16) char smem[52464];
    _Float16 (*qrelS)[72] = (_Float16(*)[72])(smem);
    _Float16 (*Pt)[72]    = (_Float16(*)[72])(smem + 18432);
    float    (*TvS)[65]   = (float(*)[65])(smem + 36864);
    float    (*binsS)[52] = (float(*)[52])(smem);

    const int t    = threadIdx.x;
    const int w    = t >> 6;
    const int lane = t & 63;
    const int lo   = lane & 15;
    const int g    = lane >> 4;
    const int gb   = g << 3;

    // ---- XCD-chunked decode: 960 blocks = 8 XCD x 24 heads x 5 q-chunks ----
    const int blk = blockIdx.x;            // 0..959
    const int x8  = blk & 7;
    const int r_  = blk >> 3;              // 0..119
    const int hq  = r_ / 5;                // 0..23
    const int qt  = r_ - hq*5;             // 0..4
    const int bh  = x8 + (hq << 3);        // head 0..191
    const int qt0 = qt * 128;
    const int qrow = 16*w + 4*g;
    const _Float16* qp = qh + (size_t)bh * (NPAD*HD);
    const _Float16* kp = kh + (size_t)bh * (NPAD*HD);
    const _Float16* vp = vh + (size_t)bh * (HD*NPAD);

    for (int e = t; e < 60*64; e += 256) {
        const int r = e >> 6, d = e & 63;
        TvS[r][d] = (r < 30) ? tvv[r*HD + d] : tvh[(r-30)*HD + d];
    }

    // ---- Q fragments for both sub-tiles (pad rows >=577 garbage, discarded) ----
    const h8 a0A = *(const h8*)(qp + (size_t)(qt0 +      16*w + lo)*HD + gb);
    const h8 a1A = *(const h8*)(qp + (size_t)(qt0 +      16*w + lo)*HD + 32 + gb);
    const h8 a0B = *(const h8*)(qp + (size_t)(qt0 + 64 + 16*w + lo)*HD + gb);
    const h8 a1B = *(const h8*)(qp + (size_t)(qt0 + 64 + 16*w + lo)*HD + 32 + gb);

    // ---- qrel for both tiles; table fragments SHARED ----
    {
        f4 qaccA[4] = {f4{0,0,0,0}, f4{0,0,0,0}, f4{0,0,0,0}, f4{0,0,0,0}};
        f4 qaccB[4] = {f4{0,0,0,0}, f4{0,0,0,0}, f4{0,0,0,0}, f4{0,0,0,0}};
        #pragma unroll
        for (int c = 0; c < 4; ++c) {
            const int r16 = 16*c + lo;
            const float* src = (r16 < 30) ? (tkv + r16*HD) : (tkh + (r16-30)*HD);
            h8 tb0 = {}, tb1 = {};
            if (r16 < 60) {
                tb0 = pack8(*(const float4*)(src + gb),      *(const float4*)(src + gb + 4));
                tb1 = pack8(*(const float4*)(src + 32 + gb), *(const float4*)(src + 32 + gb + 4));
            }
            qaccA[c] = __builtin_amdgcn_mfma_f32_16x16x32_f16(a0A, tb0, qaccA[c], 0, 0, 0);
            qaccA[c] = __builtin_amdgcn_mfma_f32_16x16x32_f16(a1A, tb1, qaccA[c], 0, 0, 0);
            qaccB[c] = __builtin_amdgcn_mfma_f32_16x16x32_f16(a0B, tb0, qaccB[c], 0, 0, 0);
            qaccB[c] = __builtin_amdgcn_mfma_f32_16x16x32_f16(a1B, tb1, qaccB[c], 0, 0, 0);
        }
        #pragma unroll
        for (int c = 0; c < 4; ++c) {
            #pragma unroll
            for (int i = 0; i < 4; ++i) {
                qrelS[qrow + i][16*c + lo]      = (_Float16)qaccA[c][i];
                qrelS[64 + qrow + i][16*c + lo] = (_Float16)qaccB[c][i];
            }
        }
    }
    // NO barrier: gathers below read only this wave's own rows.

    int qv_[2][4], qh_[2][4];
    bool q0_[2][4];
    #pragma unroll
    for (int tb = 0; tb < 2; ++tb) {
        #pragma unroll
        for (int i = 0; i < 4; ++i) {
            const int qgl = qt0 + 64*tb + qrow + i;
            q0_[tb][i] = (qgl == 0);
            int qq = qgl - 1; if (qq < 0) qq = 0;
            qv_[tb][i] = qq / 24;
            qh_[tb][i] = qq - qv_[tb][i]*24;
        }
    }

    f4 o_accA [4] = {f4{0,0,0,0}, f4{0,0,0,0}, f4{0,0,0,0}, f4{0,0,0,0}};
    f4 binaccA[4] = {f4{0,0,0,0}, f4{0,0,0,0}, f4{0,0,0,0}, f4{0,0,0,0}};
    f4 o_accB [4] = {f4{0,0,0,0}, f4{0,0,0,0}, f4{0,0,0,0}, f4{0,0,0,0}};
    f4 binaccB[4] = {f4{0,0,0,0}, f4{0,0,0,0}, f4{0,0,0,0}, f4{0,0,0,0}};

    // ================= main loop: 9 full tiles (keys 0..575) =================
    for (int kt0 = 0; kt0 < 576; kt0 += KT) {
        // ---- ONE load batch for both sub-tiles ----
        h8 kb0[4], kb1[4], v0r[4], v1r[4], m20[4], m21[4];
        #pragma unroll
        for (int c = 0; c < 4; ++c) {
            const int key = kt0 + 16*c + lo;
            kb0[c] = *(const h8*)(kp + (size_t)key*HD + gb);
            kb1[c] = *(const h8*)(kp + (size_t)key*HD + 32 + gb);
            const int dd = 16*c + lo;
            v0r[c] = *(const h8*)(vp + (size_t)dd*NPAD + kt0 + gb);
            v1r[c] = *(const h8*)(vp + (size_t)dd*NPAD + kt0 + 32 + gb);
            m20[c] = *(const h8*)(M2g + (size_t)dd*NPAD + kt0 + gb);
            m21[c] = *(const h8*)(M2g + (size_t)dd*NPAD + kt0 + 32 + gb);
        }
        // key decomposition (shared by both sub-tiles)
        int kvc[4], khc[4];
        bool kzc[4];
        #pragma unroll
        for (int c = 0; c < 4; ++c) {
            const int key = kt0 + 16*c + lo;
            int kk = key - 1; if (kk < 0) kk = 0;
            kvc[c] = kk / 24;
            khc[c] = kk - kvc[c]*24;
            kzc[c] = (key == 0);
        }
        // ---- sub-tile A: srel gather -> S -> exp -> Pt rows [0,64) ----
        {
            float srel[4][4];
            #pragma unroll
            for (int c = 0; c < 4; ++c) {
                #pragma unroll
                for (int i = 0; i < 4; ++i) {
                    int colv, colh;
                    if (kzc[c] || q0_[0][i]) { colv = 0; colh = 30; }
                    else {
                        int dv = kvc[c] - qv_[0][i]; dv = min(14, max(-14, dv));
                        int dh = khc[c] - qh_[0][i]; dh = min(14, max(-14, dh));
                        colv = dv + 15; colh = 45 + dh;
                    }
                    srel[c][i] = (float)qrelS[qrow+i][colv] + (float)qrelS[qrow+i][colh];
                }
            }
            f4 Sc[4];
            #pragma unroll
            for (int c = 0; c < 4; ++c) {
                f4 acc = f4{0,0,0,0};
                acc = __builtin_amdgcn_mfma_f32_16x16x32_f16(a0A, kb0[c], acc, 0, 0, 0);
                acc = __builtin_amdgcn_mfma_f32_16x16x32_f16(a1A, kb1[c], acc, 0, 0, 0);
                Sc[c] = acc;
            }
            #pragma unroll
            for (int c = 0; c < 4; ++c) {
                #pragma unroll
                for (int i = 0; i < 4; ++i)
                    Pt[qrow+i][16*c + lo] = (_Float16)exp2f(Sc[c][i] + srel[c][i]);
            }
        }
        // ---- sub-tile B: srel gather -> S -> exp -> Pt rows [64,128) ----
        {
            float srel[4][4];
            #pragma unroll
            for (int c = 0; c < 4; ++c) {
                #pragma unroll
                for (int i = 0; i < 4; ++i) {
                    int colv, colh;
                    if (kzc[c] || q0_[1][i]) { colv = 0; colh = 30; }
                    else {
                        int dv = kvc[c] - qv_[1][i]; dv = min(14, max(-14, dv));
                        int dh = khc[c] - qh_[1][i]; dh = min(14, max(-14, dh));
                        colv = dv + 15; colh = 45 + dh;
                    }
                    srel[c][i] = (float)qrelS[64+qrow+i][colv] + (float)qrelS[64+qrow+i][colh];
                }
            }
            f4 Sc[4];
            #pragma unroll
            for (int c = 0; c < 4; ++c) {
                f4 acc = f4{0,0,0,0};
                acc = __builtin_amdgcn_mfma_f32_16x16x32_f16(a0B, kb0[c], acc, 0, 0, 0);
                acc = __builtin_amdgcn_mfma_f32_16x16x32_f16(a1B, kb1[c], acc, 0, 0, 0);
                Sc[c] = acc;
            }
            #pragma unroll
            for (int c = 0; c < 4; ++c) {
                #pragma unroll
                for (int i = 0; i < 4; ++i)
                    Pt[64+qrow+i][16*c + lo] = (_Float16)exp2f(Sc[c][i] + srel[c][i]);
            }
        }
        // ---- P fragments + bins/PV for both sub-tiles (frags reused) ----
        const h8 p0A = *(const h8*)&Pt[16*w + lo][gb];
        const h8 p1A = *(const h8*)&Pt[16*w + lo][32 + gb];
        const h8 p0B = *(const h8*)&Pt[64 + 16*w + lo][gb];
        const h8 p1B = *(const h8*)&Pt[64 + 16*w + lo][32 + gb];
        #pragma unroll
        for (int c = 0; c < 4; ++c) {
            binaccA[c] = __builtin_amdgcn_mfma_f32_16x16x32_f16(p0A, m20[c], binaccA[c], 0, 0, 0);
            binaccA[c] = __builtin_amdgcn_mfma_f32_16x16x32_f16(p1A, m21[c], binaccA[c], 0, 0, 0);
            binaccB[c] = __builtin_amdgcn_mfma_f32_16x16x32_f16(p0B, m20[c], binaccB[c], 0, 0, 0);
            binaccB[c] = __builtin_amdgcn_mfma_f32_16x16x32_f16(p1B, m21[c], binaccB[c], 0, 0, 0);
        }
        #pragma unroll
        for (int c = 0; c < 4; ++c) {
            o_accA[c] = __builtin_amdgcn_mfma_f32_16x16x32_f16(p0A, v0r[c], o_accA[c], 0, 0, 0);
            o_accA[c] = __builtin_amdgcn_mfma_f32_16x16x32_f16(p1A, v1r[c], o_accA[c], 0, 0, 0);
            o_accB[c] = __builtin_amdgcn_mfma_f32_16x16x32_f16(p0B, v0r[c], o_accB[c], 0, 0, 0);
            o_accB[c] = __builtin_amdgcn_mfma_f32_16x16x32_f16(p1B, v1r[c], o_accB[c], 0, 0, 0);
        }
    }

    // ================= slim last tile: kt0 = 576, 1 valid key =================
    {
        const int kt0 = 576;
        h8 kb0_, kb1_, v0r[4], v1r[4], m20[4], m21[4];
        kb0_ = *(const h8*)(kp + (size_t)(kt0 + lo)*HD + gb);
        kb1_ = *(const h8*)(kp + (size_t)(kt0 + lo)*HD + 32 + gb);
        #pragma unroll
        for (int c = 0; c < 4; ++c) {
            const int dd = 16*c + lo;
            v0r[c] = *(const h8*)(vp + (size_t)dd*NPAD + kt0 + gb);
            v1r[c] = *(const h8*)(vp + (size_t)dd*NPAD + kt0 + 32 + gb);
            m20[c] = *(const h8*)(M2g + (size_t)dd*NPAD + kt0 + gb);
            m21[c] = *(const h8*)(M2g + (size_t)dd*NPAD + kt0 + 32 + gb);
        }
        const int key = kt0 + lo;
        int kk = key - 1;
        const int kv  = kk / 24;
        const int kh2 = kk - kv*24;
        const bool ok = key < NNq;
        // sub-tile A
        {
            float srel0[4];
            #pragma unroll
            for (int i = 0; i < 4; ++i) {
                int colv, colh;
                if (q0_[0][i]) { colv = 0; colh = 30; }
                else {
                    int dv = kv  - qv_[0][i]; dv = min(14, max(-14, dv));
                    int dh = kh2 - qh_[0][i]; dh = min(14, max(-14, dh));
                    colv = dv + 15; colh = 45 + dh;
                }
                srel0[i] = (float)qrelS[qrow+i][colv] + (float)qrelS[qrow+i][colh];
            }
            f4 Sc0 = f4{0,0,0,0};
            Sc0 = __builtin_amdgcn_mfma_f32_16x16x32_f16(a0A, kb0_, Sc0, 0, 0, 0);
            Sc0 = __builtin_amdgcn_mfma_f32_16x16x32_f16(a1A, kb1_, Sc0, 0, 0, 0);
            #pragma unroll
            for (int i = 0; i < 4; ++i)
                Pt[qrow+i][lo] = (_Float16)(ok ? exp2f(Sc0[i] + srel0[i]) : 0.f);
            #pragma unroll
            for (int c = 1; c < 4; ++c)
                #pragma unroll
                for (int i = 0; i < 4; ++i) Pt[qrow+i][16*c + lo] = (_Float16)0.f;
        }
        // sub-tile B
        {
            float srel0[4];
            #pragma unroll
            for (int i = 0; i < 4; ++i) {
                int colv, colh;
                if (q0_[1][i]) { colv = 0; colh = 30; }
                else {
                    int dv = kv  - qv_[1][i]; dv = min(14, max(-14, dv));
                    int dh = kh2 - qh_[1][i]; dh = min(14, max(-14, dh));
                    colv = dv + 15; colh = 45 + dh;
                }
                srel0[i] = (float)qrelS[64+qrow+i][colv] + (float)qrelS[64+qrow+i][colh];
            }
            f4 Sc0 = f4{0,0,0,0};
            Sc0 = __builtin_amdgcn_mfma_f32_16x16x32_f16(a0B, kb0_, Sc0, 0, 0, 0);
            Sc0 = __builtin_amdgcn_mfma_f32_16x16x32_f16(a1B, kb1_, Sc0, 0, 0, 0);
            #pragma unroll
            for (int i = 0; i < 4; ++i)
                Pt[64+qrow+i][lo] = (_Float16)(ok ? exp2f(Sc0[i] + srel0[i]) : 0.f);
            #pragma unroll
            for (int c = 1; c < 4; ++c)
                #pragma unroll
                for (int i = 0; i < 4; ++i) Pt[64+qrow+i][16*c + lo] = (_Float16)0.f;
        }
        const h8 p0A = *(const h8*)&Pt[16*w + lo][gb];
        const h8 p1A = *(const h8*)&Pt[16*w + lo][32 + gb];
        const h8 p0B = *(const h8*)&Pt[64 + 16*w + lo][gb];
        const h8 p1B = *(const h8*)&Pt[64 + 16*w + lo][32 + gb];
        #pragma unroll
        for (int c = 0; c < 4; ++c) {
            binaccA[c] = __builtin_amdgcn_mfma_f32_16x16x32_f16(p0A, m20[c], binaccA[c], 0, 0, 0);
            binaccA[c] = __builtin_amdgcn_mfma_f32_16x16x32_f16(p1A, m21[c], binaccA[c], 0, 0, 0);
            binaccB[c] = __builtin_amdgcn_mfma_f32_16x16x32_f16(p0B, m20[c], binaccB[c], 0, 0, 0);
            binaccB[c] = __builtin_amdgcn_mfma_f32_16x16x32_f16(p1B, m21[c], binaccB[c], 0, 0, 0);
        }
        #pragma unroll
        for (int c = 0; c < 4; ++c) {
            o_accA[c] = __builtin_amdgcn_mfma_f32_16x16x32_f16(p0A, v0r[c], o_accA[c], 0, 0, 0);
            o_accA[c] = __builtin_amdgcn_mfma_f32_16x16x32_f16(p1A, v1r[c], o_accA[c], 0, 0, 0);
            o_accB[c] = __builtin_amdgcn_mfma_f32_16x16x32_f16(p0B, v0r[c], o_accB[c], 0, 0, 0);
            o_accB[c] = __builtin_amdgcn_mfma_f32_16x16x32_f16(p1B, v1r[c], o_accB[c], 0, 0, 0);
        }
    }

    // ---- epilogue ----
    __syncthreads();
    #pragma unroll
    for (int c = 0; c < 4; ++c) {
        const int bc = 16*c + lo;
        if (bc <= 50) {
            #pragma unroll
            for (int i = 0; i < 4; ++i) {
                binsS[qrow+i][bc]      = binaccA[c][i];
                binsS[64+qrow+i][bc]   = binaccB[c][i];
            }
        }
    }
    __syncthreads();

    const int b_ = bh / NHh;
    const int h_ = bh - b_*NHh;
    #pragma unroll
    for (int tb = 0; tb < 2; ++tb) {
        #pragma unroll
        for (int i = 0; i < 4; ++i) {
            const int qr  = 64*tb + qrow + i;
            const int qgl = qt0 + qr;
            if (qgl >= NNq) continue;
            const float l    = binsS[qr][50];
            const float invl = 1.f / l;
            const f4* oa = tb ? o_accB : o_accA;
            float o[4] = {oa[0][i], oa[1][i], oa[2][i], oa[3][i]};
            if (qgl == 0) {
                #pragma unroll
                for (int c = 0; c < 4; ++c) {
                    const int d = 16*c + lo;
                    o[c] += l * (TvS[0][d] + TvS[30][d]);
                }
            } else {
                #pragma unroll
                for (int bin = 0; bin < 24; ++bin) {
                    const float wq = binsS[qr][bin];
                    int dv = bin - qv_[tb][i]; dv = min(14, max(-14, dv));
                    #pragma unroll
                    for (int c = 0; c < 4; ++c) o[c] += wq * TvS[dv+15][16*c + lo];
                }
                {
                    const float wq = binsS[qr][24];
                    #pragma unroll
                    for (int c = 0; c < 4; ++c) o[c] += wq * TvS[0][16*c + lo];
                }
                #pragma unroll
                for (int bin = 0; bin < 24; ++bin) {
                    const float wq = binsS[qr][25+bin];
                    int dh = bin - qh_[tb][i]; dh = min(14, max(-14, dh));
                    #pragma unroll
                    for (int c = 0; c < 4; ++c) o[c] += wq * TvS[45+dh][16*c + lo];
                }
                {
                    const float wq = binsS[qr][49];
                    #pragma unroll
                    for (int c = 0; c < 4; ++c) o[c] += wq * TvS[30][16*c + lo];
                }
            }
            _Float16* dst = aoh + (size_t)(b_*NNq + qgl)*DIMM + h_*HD;
            #pragma unroll
            for (int c = 0; c < 4; ++c) dst[16*c + lo] = (_Float16)(o[c] * invl);
        }
    }
}

// ---------------------------------------------------------------- launcher
extern "C" void kernel_launch(void* const* d_in, const int* in_sizes, int n_in,
                              void* d_out, int out_size, void* d_ws, size_t ws_size,
                              hipStream_t stream)
{
    const float* x      = (const float*)d_in[0];
    const float* qkv_w  = (const float*)d_in[1];
    const float* proj_w = (const float*)d_in[2];
    const float* proj_b = (const float*)d_in[3];
    const float* tkv    = (const float*)d_in[4];
    const float* tkh    = (const float*)d_in[5];
    const float* tvv    = (const float*)d_in[6];
    const float* tvh    = (const float*)d_in[7];
    float* out = (float*)d_out;
    float* ws  = (float*)d_ws;

    const size_t KV = (size_t)BB * NHh * NPAD * HD;      // 7,864,320 halves per tensor
    _Float16* qh  = (_Float16*)ws;
    _Float16* kh  = qh + KV;
    _Float16* vh  = kh + KV;
    _Float16* aoh = vh + KV;                              // MM*DIMM halves
    _Float16* M2g = aoh + (size_t)MM*DIMM;
    _Float16* xh  = M2g + NPAD*64;
    _Float16* wh  = xh + (size_t)MM*DIMM;
    _Float16* pwh = wh + (size_t)NW3*DIMM;

    dim3 b256(256, 1, 1);
    // 40960 (M2) + 786432 (vpad) + 2362368 (converts) = 3189760 = 12460 * 256
    init_all<<<12460, b256, 0, stream>>>(x, qkv_w, proj_w, M2g, vh, xh, wh, pwh);

    dim3 g1(NW3/128, (MM + 127)/128, 1);                 // 18 x 73
    qkv_gemm<<<g1, b256, 0, stream>>>(xh, wh, qh, kh, vh);

    // 192 heads x 5 q-chunks of 128 rows, XCD-chunked
    attn_fused<<<dim3(960,1,1), b256, 0, stream>>>(qh, kh, vh, tkv, tkh, tvv, tvh, M2g, aoh);

    dim3 g3(DIMM/128, (MM + 127)/128, 1);                // 6 x 73
    proj_gemm<<<g3, b256, 0, stream>>>(aoh, pwh, proj_b, out);
}

// Round 18
// 429.745 us; speedup vs baseline: 1.0466x; 1.0466x over previous
//
#include <hip/hip_runtime.h>

// Attention_11845519803093 — R24: R22 restored (banked 433.0us) + s_setprio on attn MFMAs.
//   * R23 post-mortem: allocator pins VGPR=128 at (256,2) regardless of demand;
//     2-q-tile state (~210 VGPR) spilled (WRITE 13.8->44.3MB). Reverted.
//   * T5 graft: setprio(1) around attn MFMA clusters. Evidence: +4-7% on
//     barrier-free attn with drifting waves (null on lockstep GEMM) — our
//     attn K-loop is exactly the former. Zero register/LDS cost.
//   * GEMMs BK=64 staged, init_all, attn srel-hoist + slim tail: R22 verbatim.
// ws layout: qh | kh | vh | aoh | M2 | xh | wh | pwh

#define BB    16
#define NNq   577
#define DIMM  768
#define NHh   12
#define HD    64
#define MM    9232
#define QT    64
#define KT    64
#define NPAD  640
#define NW3   2304

typedef _Float16 h8 __attribute__((ext_vector_type(8)));
typedef _Float16 h4 __attribute__((ext_vector_type(4)));
typedef float    f4 __attribute__((ext_vector_type(4)));

__device__ inline h8 pack8(float4 a, float4 b) {
    h8 r;
    r[0]=(_Float16)a.x; r[1]=(_Float16)a.y; r[2]=(_Float16)a.z; r[3]=(_Float16)a.w;
    r[4]=(_Float16)b.x; r[5]=(_Float16)b.y; r[6]=(_Float16)b.z; r[7]=(_Float16)b.w;
    return r;
}

// ---------------------------------------------------------------- merged init
__global__ void init_all(const float* __restrict__ x, const float* __restrict__ w,
                         const float* __restrict__ pw,
                         _Float16* __restrict__ M2g, _Float16* __restrict__ vh,
                         _Float16* __restrict__ xh, _Float16* __restrict__ wh,
                         _Float16* __restrict__ pwh)
{
    const size_t id = (size_t)blockIdx.x*256 + threadIdx.x;
    if (id < NPAD*64) {
        const int key = (int)id >> 6, bin = (int)id & 63;
        int vb = 255, hb = 255;
        if (key == 0)      { vb = 24; hb = 49; }
        else if (key < NNq){ const int kq = key-1, kv = kq/24; vb = kv; hb = 25 + (kq - kv*24); }
        M2g[bin*NPAD + key] =
            ((key < NNq) && (bin==vb || bin==hb || bin==50)) ? (_Float16)1.f : (_Float16)0.f;
        return;
    }
    const size_t vid = id - NPAD*64;
    if (vid < (size_t)BB*NHh*HD*64) {
        const int head = (int)(vid >> 12);
        const int rem  = (int)vid & 4095;
        const int d    = rem >> 6;
        const int col  = 576 + (rem & 63);
        vh[(size_t)head*(HD*NPAD) + (size_t)d*NPAD + col] = (_Float16)0.f;
        return;
    }
    const size_t cid = vid - (size_t)BB*NHh*HD*64;
    const size_t NX = (size_t)MM*DIMM/4;
    const size_t NW = (size_t)NW3*DIMM/4;
    const size_t NP = (size_t)DIMM*DIMM/4;
    const float4* src; h4* dst; size_t j;
    if (cid < NX)            { src = (const float4*)x;  dst = (h4*)xh;  j = cid; }
    else if (cid < NX+NW)    { src = (const float4*)w;  dst = (h4*)wh;  j = cid - NX; }
    else if (cid < NX+NW+NP) { src = (const float4*)pw; dst = (h4*)pwh; j = cid - NX - NW; }
    else return;
    const float4 v = src[j];
    h4 hh; hh[0]=(_Float16)v.x; hh[1]=(_Float16)v.y; hh[2]=(_Float16)v.z; hh[3]=(_Float16)v.w;
    dst[j] = hh;
}

// ---------------------------------------------------------------- BK=64 staged fp16 GEMM core
template <typename F>
__device__ __forceinline__ void gemm128f2(const _Float16* __restrict__ Ah_g,
                                          const _Float16* __restrict__ Bh_g,
                                          F epi)
{
    __shared__ _Float16 Ah[128][72], Bh[128][72];
    const int t  = threadIdx.x;
    const int wv = t >> 6, lane = t & 63, lo = lane & 15, g = lane >> 4;
    const int gb = g << 3;
    const int wm = (wv >> 1) << 6, wn = (wv & 1) << 6;
    const int bm = blockIdx.y << 7, bn = blockIdx.x << 7;
    f4 acc[4][4] = {};
    const int lr = t >> 1;
    const int lc = (t & 1) << 5;          // 0 or 32
    const int am = bm + lr;
    const bool aok = am < MM;
    const _Float16* arh = Ah_g + (size_t)(aok ? am : 0) * DIMM + lc;
    const _Float16* brh = Bh_g + (size_t)(bn + lr) * DIMM + lc;

    for (int k0 = 0; k0 < DIMM; k0 += 64) {
        h8 a0 = {}, a1 = {}, a2 = {}, a3 = {};
        if (aok) {
            a0 = *(const h8*)(arh + k0);      a1 = *(const h8*)(arh + k0 + 8);
            a2 = *(const h8*)(arh + k0 + 16); a3 = *(const h8*)(arh + k0 + 24);
        }
        const h8 b0 = *(const h8*)(brh + k0),      b1 = *(const h8*)(brh + k0 + 8);
        const h8 b2 = *(const h8*)(brh + k0 + 16), b3 = *(const h8*)(brh + k0 + 24);
        __syncthreads();
        *(h8*)&Ah[lr][lc]    = a0; *(h8*)&Ah[lr][lc+8]  = a1;
        *(h8*)&Ah[lr][lc+16] = a2; *(h8*)&Ah[lr][lc+24] = a3;
        *(h8*)&Bh[lr][lc]    = b0; *(h8*)&Bh[lr][lc+8]  = b1;
        *(h8*)&Bh[lr][lc+16] = b2; *(h8*)&Bh[lr][lc+24] = b3;
        __syncthreads();
        {
            h8 fah[4], fbh[4];
            #pragma unroll
            for (int i = 0; i < 4; ++i) {
                fah[i] = *(const h8*)&Ah[wm + 16*i + lo][gb];
                fbh[i] = *(const h8*)&Bh[wn + 16*i + lo][gb];
            }
            #pragma unroll
            for (int mi = 0; mi < 4; ++mi) {
                #pragma unroll
                for (int ni = 0; ni < 4; ++ni)
                    acc[mi][ni] = __builtin_amdgcn_mfma_f32_16x16x32_f16(fah[mi], fbh[ni], acc[mi][ni], 0, 0, 0);
            }
        }
        {
            h8 fah[4], fbh[4];
            #pragma unroll
            for (int i = 0; i < 4; ++i) {
                fah[i] = *(const h8*)&Ah[wm + 16*i + lo][32 + gb];
                fbh[i] = *(const h8*)&Bh[wn + 16*i + lo][32 + gb];
            }
            #pragma unroll
            for (int mi = 0; mi < 4; ++mi) {
                #pragma unroll
                for (int ni = 0; ni < 4; ++ni)
                    acc[mi][ni] = __builtin_amdgcn_mfma_f32_16x16x32_f16(fah[mi], fbh[ni], acc[mi][ni], 0, 0, 0);
            }
        }
    }
    epi(acc, bm, bn, wm, wn, lo, g);
}

// ---------------------------------------------------------------- QKV GEMM
__global__ __launch_bounds__(256, 3)
void qkv_gemm(const _Float16* __restrict__ xh, const _Float16* __restrict__ wh,
              _Float16* __restrict__ qh, _Float16* __restrict__ kh, _Float16* __restrict__ vh)
{
    gemm128f2(xh, wh, [=](f4 (&acc)[4][4], int bm, int bn, int wm, int wn, int lo, int g) {
        const int three = bn / 768;
        const int cb    = bn - three * 768;
        #pragma unroll
        for (int mi = 0; mi < 4; ++mi) {
            #pragma unroll
            for (int reg = 0; reg < 4; ++reg) {
                const int m = bm + wm + 16*mi + 4*g + reg;
                if (m >= MM) continue;
                const int b_ = m / NNq;
                const int n_ = m - b_ * NNq;
                #pragma unroll
                for (int ni = 0; ni < 4; ++ni) {
                    const int n  = cb + wn + 16*ni + lo;
                    const int hh = n >> 6;
                    const int d  = n & 63;
                    if (three == 0) {
                        // Q scaled 0.125 * log2(e) for the exp2 path
                        qh[((size_t)(b_*NHh + hh)*NPAD + n_)*HD + d] =
                            (_Float16)(acc[mi][ni][reg] * 0.18033688f);
                    } else if (three == 1) {
                        kh[((size_t)(b_*NHh + hh)*NPAD + n_)*HD + d] = (_Float16)acc[mi][ni][reg];
                    } else {
                        vh[((size_t)(b_*NHh + hh)*HD + d)*NPAD + n_] = (_Float16)acc[mi][ni][reg];
                    }
                }
            }
        }
    });
}

// ---------------------------------------------------------------- proj GEMM
__global__ __launch_bounds__(256, 3)
void proj_gemm(const _Float16* __restrict__ aoh, const _Float16* __restrict__ pwh,
               const float* __restrict__ bias, float* __restrict__ out)
{
    gemm128f2(aoh, pwh, [=](f4 (&acc)[4][4], int bm, int bn, int wm, int wn, int lo, int g) {
        #pragma unroll
        for (int ni = 0; ni < 4; ++ni) {
            const int n  = bn + wn + 16*ni + lo;
            const float bb = bias[n];
            #pragma unroll
            for (int mi = 0; mi < 4; ++mi) {
                #pragma unroll
                for (int reg = 0; reg < 4; ++reg) {
                    const int m = bm + wm + 16*mi + 4*g + reg;
                    if (m >= MM) continue;
                    out[(size_t)m*DIMM + n] = acc[mi][ni][reg] + bb;
                }
            }
        }
    });
}

// ---------------------------------------------------------------- fused attention (R20/R22 + setprio)
__global__ __launch_bounds__(256, 2)
void attn_fused(const _Float16* __restrict__ qh,
                const _Float16* __restrict__ kh, const _Float16* __restrict__ vh,
                const float* __restrict__ tkv, const float* __restrict__ tkh,
                const float* __restrict__ tvv, const float* __restrict__ tvh,
                const _Float16* __restrict__ M2g,
                _Float16* __restrict__ aoh)
{
    __shared__ __align__(16) char smem[34048];
    _Float16 (*qrelS)[72] = (_Float16(*)[72])(smem);
    _Float16 (*Pt)[72]    = (_Float16(*)[72])(smem + 9216);
    float    (*TvS)[65]   = (float(*)[65])(smem + 18432);
    float    (*binsS)[52] = (float(*)[52])(smem);

    const int t    = threadIdx.x;
    const int w    = t >> 6;
    const int lane = t & 63;
    const int lo   = lane & 15;
    const int g    = lane >> 4;
    const int gb   = g << 3;

    const int blk = blockIdx.x;            // 0..1919
    const int x8  = blk & 7;
    const int r_  = blk >> 3;              // 0..239
    const int hq  = r_ / 10;               // 0..23
    const int qt  = r_ - hq*10;            // 0..9
    const int bh  = x8 + (hq << 3);        // head 0..191
    const int qt0 = qt * QT;
    const int qrow = 16*w + 4*g;
    const _Float16* qp = qh + (size_t)bh * (NPAD*HD);
    const _Float16* kp = kh + (size_t)bh * (NPAD*HD);
    const _Float16* vp = vh + (size_t)bh * (HD*NPAD);

    for (int e = t; e < 60*64; e += 256) {
        const int r = e >> 6, d = e & 63;
        TvS[r][d] = (r < 30) ? tvv[r*HD + d] : tvh[(r-30)*HD + d];
    }

    const h8 a0 = *(const h8*)(qp + (size_t)(qt0 + 16*w + lo)*HD + gb);
    const h8 a1 = *(const h8*)(qp + (size_t)(qt0 + 16*w + lo)*HD + 32 + gb);

    {
        f4 qacc[4] = {f4{0,0,0,0}, f4{0,0,0,0}, f4{0,0,0,0}, f4{0,0,0,0}};
        #pragma unroll
        for (int c = 0; c < 4; ++c) {
            const int r16 = 16*c + lo;
            const float* src = (r16 < 30) ? (tkv + r16*HD) : (tkh + (r16-30)*HD);
            h8 tb0 = {}, tb1 = {};
            if (r16 < 60) {
                tb0 = pack8(*(const float4*)(src + gb),      *(const float4*)(src + gb + 4));
                tb1 = pack8(*(const float4*)(src + 32 + gb), *(const float4*)(src + 32 + gb + 4));
            }
            qacc[c] = __builtin_amdgcn_mfma_f32_16x16x32_f16(a0, tb0, qacc[c], 0, 0, 0);
            qacc[c] = __builtin_amdgcn_mfma_f32_16x16x32_f16(a1, tb1, qacc[c], 0, 0, 0);
        }
        #pragma unroll
        for (int c = 0; c < 4; ++c) {
            #pragma unroll
            for (int i = 0; i < 4; ++i)
                qrelS[qrow + i][16*c + lo] = (_Float16)qacc[c][i];
        }
    }
    // NO barrier: gather below reads only this wave's own rows.

    int qv_[4], qh_[4];
    bool q0_[4];
    #pragma unroll
    for (int i = 0; i < 4; ++i) {
        const int qgl = qt0 + qrow + i;
        q0_[i] = (qgl == 0);
        int qq = qgl - 1; if (qq < 0) qq = 0;
        qv_[i] = qq / 24;
        qh_[i] = qq - qv_[i]*24;
    }

    f4 o_acc [4] = {f4{0,0,0,0}, f4{0,0,0,0}, f4{0,0,0,0}, f4{0,0,0,0}};
    f4 binacc[4] = {f4{0,0,0,0}, f4{0,0,0,0}, f4{0,0,0,0}, f4{0,0,0,0}};

    // ================= main loop: 9 full tiles (keys 0..575) =================
    for (int kt0 = 0; kt0 < 576; kt0 += KT) {
        h8 kb0[4], kb1[4], v0r[4], v1r[4], m20[4], m21[4];
        #pragma unroll
        for (int c = 0; c < 4; ++c) {
            const int key = kt0 + 16*c + lo;
            kb0[c] = *(const h8*)(kp + (size_t)key*HD + gb);
            kb1[c] = *(const h8*)(kp + (size_t)key*HD + 32 + gb);
            const int dd = 16*c + lo;
            v0r[c] = *(const h8*)(vp + (size_t)dd*NPAD + kt0 + gb);
            v1r[c] = *(const h8*)(vp + (size_t)dd*NPAD + kt0 + 32 + gb);
            m20[c] = *(const h8*)(M2g + (size_t)dd*NPAD + kt0 + gb);
            m21[c] = *(const h8*)(M2g + (size_t)dd*NPAD + kt0 + 32 + gb);
        }
        // ---- srel-hoist: LDS gather BEFORE the MFMAs (hides under vmcnt) ----
        float srel[4][4];
        #pragma unroll
        for (int c = 0; c < 4; ++c) {
            const int key = kt0 + 16*c + lo;
            int kk = key - 1; if (kk < 0) kk = 0;
            const int kv  = kk / 24;
            const int kh2 = kk - kv*24;
            const bool kz = (key == 0);
            #pragma unroll
            for (int i = 0; i < 4; ++i) {
                int colv, colh;
                if (kz || q0_[i]) { colv = 0; colh = 30; }
                else {
                    int dv = kv  - qv_[i]; dv = min(14, max(-14, dv));
                    int dh = kh2 - qh_[i]; dh = min(14, max(-14, dh));
                    colv = dv + 15;
                    colh = 45 + dh;
                }
                srel[c][i] = (float)qrelS[qrow+i][colv] + (float)qrelS[qrow+i][colh];
            }
        }
        // ---- S = Q·K^T (MFMA, log2 units), scheduler-prioritized ----
        __builtin_amdgcn_s_setprio(1);
        f4 Sc[4];
        #pragma unroll
        for (int c = 0; c < 4; ++c) {
            f4 acc = f4{0,0,0,0};
            acc = __builtin_amdgcn_mfma_f32_16x16x32_f16(a0, kb0[c], acc, 0, 0, 0);
            acc = __builtin_amdgcn_mfma_f32_16x16x32_f16(a1, kb1[c], acc, 0, 0, 0);
            Sc[c] = acc;
        }
        __builtin_amdgcn_s_setprio(0);
        // ---- P = exp2(S + srel) ----
        #pragma unroll
        for (int c = 0; c < 4; ++c) {
            #pragma unroll
            for (int i = 0; i < 4; ++i) {
                const float p = exp2f(Sc[c][i] + srel[c][i]);
                Pt[qrow+i][16*c + lo] = (_Float16)p;
            }
        }
        // ---- P fragments (own wave's rows; lgkmcnt ordering only) ----
        const h8 p0 = *(const h8*)&Pt[16*w + lo][gb];
        const h8 p1 = *(const h8*)&Pt[16*w + lo][32 + gb];
        // ---- bins += P @ M2^T ; O += P @ V (prioritized MFMA burst) ----
        __builtin_amdgcn_s_setprio(1);
        #pragma unroll
        for (int c = 0; c < 4; ++c) {
            binacc[c] = __builtin_amdgcn_mfma_f32_16x16x32_f16(p0, m20[c], binacc[c], 0, 0, 0);
            binacc[c] = __builtin_amdgcn_mfma_f32_16x16x32_f16(p1, m21[c], binacc[c], 0, 0, 0);
        }
        #pragma unroll
        for (int c = 0; c < 4; ++c) {
            o_acc[c] = __builtin_amdgcn_mfma_f32_16x16x32_f16(p0, v0r[c], o_acc[c], 0, 0, 0);
            o_acc[c] = __builtin_amdgcn_mfma_f32_16x16x32_f16(p1, v1r[c], o_acc[c], 0, 0, 0);
        }
        __builtin_amdgcn_s_setprio(0);
    }

    // ================= slim last tile: kt0 = 576, 1 valid key =================
    {
        const int kt0 = 576;
        h8 kb0_, kb1_, v0r[4], v1r[4], m20[4], m21[4];
        kb0_ = *(const h8*)(kp + (size_t)(kt0 + lo)*HD + gb);
        kb1_ = *(const h8*)(kp + (size_t)(kt0 + lo)*HD + 32 + gb);
        #pragma unroll
        for (int c = 0; c < 4; ++c) {
            const int dd = 16*c + lo;
            v0r[c] = *(const h8*)(vp + (size_t)dd*NPAD + kt0 + gb);
            v1r[c] = *(const h8*)(vp + (size_t)dd*NPAD + kt0 + 32 + gb);
            m20[c] = *(const h8*)(M2g + (size_t)dd*NPAD + kt0 + gb);
            m21[c] = *(const h8*)(M2g + (size_t)dd*NPAD + kt0 + 32 + gb);
        }
        float srel0[4];
        {
            const int key = kt0 + lo;
            int kk = key - 1; if (kk < 0) kk = 0;
            const int kv  = kk / 24;
            const int kh2 = kk - kv*24;
            #pragma unroll
            for (int i = 0; i < 4; ++i) {
                int colv, colh;
                if (q0_[i]) { colv = 0; colh = 30; }
                else {
                    int dv = kv  - qv_[i]; dv = min(14, max(-14, dv));
                    int dh = kh2 - qh_[i]; dh = min(14, max(-14, dh));
                    colv = dv + 15;
                    colh = 45 + dh;
                }
                srel0[i] = (float)qrelS[qrow+i][colv] + (float)qrelS[qrow+i][colh];
            }
        }
        f4 Sc0 = f4{0,0,0,0};
        Sc0 = __builtin_amdgcn_mfma_f32_16x16x32_f16(a0, kb0_, Sc0, 0, 0, 0);
        Sc0 = __builtin_amdgcn_mfma_f32_16x16x32_f16(a1, kb1_, Sc0, 0, 0, 0);
        {
            const bool ok = (kt0 + lo) < NNq;
            #pragma unroll
            for (int i = 0; i < 4; ++i) {
                const float p = ok ? exp2f(Sc0[i] + srel0[i]) : 0.f;
                Pt[qrow+i][lo] = (_Float16)p;
            }
            #pragma unroll
            for (int c = 1; c < 4; ++c) {
                #pragma unroll
                for (int i = 0; i < 4; ++i)
                    Pt[qrow+i][16*c + lo] = (_Float16)0.f;
            }
        }
        const h8 p0 = *(const h8*)&Pt[16*w + lo][gb];
        const h8 p1 = *(const h8*)&Pt[16*w + lo][32 + gb];
        #pragma unroll
        for (int c = 0; c < 4; ++c) {
            binacc[c] = __builtin_amdgcn_mfma_f32_16x16x32_f16(p0, m20[c], binacc[c], 0, 0, 0);
            binacc[c] = __builtin_amdgcn_mfma_f32_16x16x32_f16(p1, m21[c], binacc[c], 0, 0, 0);
        }
        #pragma unroll
        for (int c = 0; c < 4; ++c) {
            o_acc[c] = __builtin_amdgcn_mfma_f32_16x16x32_f16(p0, v0r[c], o_acc[c], 0, 0, 0);
            o_acc[c] = __builtin_amdgcn_mfma_f32_16x16x32_f16(p1, v1r[c], o_acc[c], 0, 0, 0);
        }
    }

    // ---- epilogue ----
    __syncthreads();
    #pragma unroll
    for (int c = 0; c < 4; ++c) {
        const int bc = 16*c + lo;
        if (bc <= 50) {
            #pragma unroll
            for (int i = 0; i < 4; ++i) binsS[qrow+i][bc] = binacc[c][i];
        }
    }
    __syncthreads();

    const int b_ = bh / NHh;
    const int h_ = bh - b_*NHh;
    #pragma unroll
    for (int i = 0; i < 4; ++i) {
        const int qr  = qrow + i;
        const int qgl = qt0 + qr;
        if (qgl >= NNq) continue;
        const float l    = binsS[qr][50];
        const float invl = 1.f / l;
        float o[4] = {o_acc[0][i], o_acc[1][i], o_acc[2][i], o_acc[3][i]};
        if (qgl == 0) {
            #pragma unroll
            for (int c = 0; c < 4; ++c) {
                const int d = 16*c + lo;
                o[c] += l * (TvS[0][d] + TvS[30][d]);
            }
        } else {
            #pragma unroll
            for (int bin = 0; bin < 24; ++bin) {
                const float wq = binsS[qr][bin];
                int dv = bin - qv_[i]; dv = min(14, max(-14, dv));
                #pragma unroll
                for (int c = 0; c < 4; ++c) o[c] += wq * TvS[dv+15][16*c + lo];
            }
            {
                const float wq = binsS[qr][24];
                #pragma unroll
                for (int c = 0; c < 4; ++c) o[c] += wq * TvS[0][16*c + lo];
            }
            #pragma unroll
            for (int bin = 0; bin < 24; ++bin) {
                const float wq = binsS[qr][25+bin];
                int dh = bin - qh_[i]; dh = min(14, max(-14, dh));
                #pragma unroll
                for (int c = 0; c < 4; ++c) o[c] += wq * TvS[45+dh][16*c + lo];
            }
            {
                const float wq = binsS[qr][49];
                #pragma unroll
                for (int c = 0; c < 4; ++c) o[c] += wq * TvS[30][16*c + lo];
            }
        }
        _Float16* dst = aoh + (size_t)(b_*NNq + qgl)*DIMM + h_*HD;
        #pragma unroll
        for (int c = 0; c < 4; ++c) dst[16*c + lo] = (_Float16)(o[c] * invl);
    }
}

// ---------------------------------------------------------------- launcher
extern "C" void kernel_launch(void* const* d_in, const int* in_sizes, int n_in,
                              void* d_out, int out_size, void* d_ws, size_t ws_size,
                              hipStream_t stream)
{
    const float* x      = (const float*)d_in[0];
    const float* qkv_w  = (const float*)d_in[1];
    const float* proj_w = (const float*)d_in[2];
    const float* proj_b = (const float*)d_in[3];
    const float* tkv    = (const float*)d_in[4];
    const float* tkh    = (const float*)d_in[5];
    const float* tvv    = (const float*)d_in[6];
    const float* tvh    = (const float*)d_in[7];
    float* out = (float*)d_out;
    float* ws  = (float*)d_ws;

    const size_t KV = (size_t)BB * NHh * NPAD * HD;      // 7,864,320 halves per tensor
    _Float16* qh  = (_Float16*)ws;
    _Float16* kh  = qh + KV;
    _Float16* vh  = kh + KV;
    _Float16* aoh = vh + KV;                              // MM*DIMM halves
    _Float16* M2g = aoh + (size_t)MM*DIMM;
    _Float16* xh  = M2g + NPAD*64;
    _Float16* wh  = xh + (size_t)MM*DIMM;
    _Float16* pwh = wh + (size_t)NW3*DIMM;

    dim3 b256(256, 1, 1);
    // 40960 (M2) + 786432 (vpad) + 2362368 (converts) = 3189760 = 12460 * 256
    init_all<<<12460, b256, 0, stream>>>(x, qkv_w, proj_w, M2g, vh, xh, wh, pwh);

    dim3 g1(NW3/128, (MM + 127)/128, 1);                 // 18 x 73
    qkv_gemm<<<g1, b256, 0, stream>>>(xh, wh, qh, kh, vh);

    attn_fused<<<dim3(1920,1,1), b256, 0, stream>>>(qh, kh, vh, tkv, tkh, tvv, tvh, M2g, aoh);

    dim3 g3(DIMM/128, (MM + 127)/128, 1);                // 6 x 73
    proj_gemm<<<g3, b256, 0, stream>>>(aoh, pwh, proj_b, out);
}

// Round 19
// 387.263 us; speedup vs baseline: 1.1614x; 1.1097x over previous
//
#include <hip/hip_runtime.h>

// Attention_11845519803093 — R25: R23's 2-q-tile attn + amdgpu_waves_per_eu(2,2).
//   * R23 failed ONLY because __launch_bounds__(256,2) sets a MINIMUM waves/EU;
//     allocator aimed at 4 waves/SIMD -> pinned VGPR=128 -> ~210-VGPR state spilled
//     (WRITE 44MB). waves_per_eu(2,2) sets min AND MAX -> true 256-VGPR budget.
//   * attn: 2 q-tiles per wave, ONE shared K/V/M2 load batch per k-tile (loads
//     per MFMA halved), 960 blocks, setprio MFMA clusters (R24), slim last tile.
//   * Revert rule: VGPR==128 (attr ignored) or WRITE>20MB (spill) -> R24 final.
//   * GEMMs (BK=64 staged, (256,3)) + init_all = R24 verbatim.
// ws layout: qh | kh | vh | aoh | M2 | xh | wh | pwh

#define BB    16
#define NNq   577
#define DIMM  768
#define NHh   12
#define HD    64
#define MM    9232
#define KT    64
#define NPAD  640
#define NW3   2304

typedef _Float16 h8 __attribute__((ext_vector_type(8)));
typedef _Float16 h4 __attribute__((ext_vector_type(4)));
typedef float    f4 __attribute__((ext_vector_type(4)));

__device__ inline h8 pack8(float4 a, float4 b) {
    h8 r;
    r[0]=(_Float16)a.x; r[1]=(_Float16)a.y; r[2]=(_Float16)a.z; r[3]=(_Float16)a.w;
    r[4]=(_Float16)b.x; r[5]=(_Float16)b.y; r[6]=(_Float16)b.z; r[7]=(_Float16)b.w;
    return r;
}

// ---------------------------------------------------------------- merged init
__global__ void init_all(const float* __restrict__ x, const float* __restrict__ w,
                         const float* __restrict__ pw,
                         _Float16* __restrict__ M2g, _Float16* __restrict__ vh,
                         _Float16* __restrict__ xh, _Float16* __restrict__ wh,
                         _Float16* __restrict__ pwh)
{
    const size_t id = (size_t)blockIdx.x*256 + threadIdx.x;
    if (id < NPAD*64) {
        const int key = (int)id >> 6, bin = (int)id & 63;
        int vb = 255, hb = 255;
        if (key == 0)      { vb = 24; hb = 49; }
        else if (key < NNq){ const int kq = key-1, kv = kq/24; vb = kv; hb = 25 + (kq - kv*24); }
        M2g[bin*NPAD + key] =
            ((key < NNq) && (bin==vb || bin==hb || bin==50)) ? (_Float16)1.f : (_Float16)0.f;
        return;
    }
    const size_t vid = id - NPAD*64;
    if (vid < (size_t)BB*NHh*HD*64) {
        const int head = (int)(vid >> 12);
        const int rem  = (int)vid & 4095;
        const int d    = rem >> 6;
        const int col  = 576 + (rem & 63);
        vh[(size_t)head*(HD*NPAD) + (size_t)d*NPAD + col] = (_Float16)0.f;
        return;
    }
    const size_t cid = vid - (size_t)BB*NHh*HD*64;
    const size_t NX = (size_t)MM*DIMM/4;
    const size_t NW = (size_t)NW3*DIMM/4;
    const size_t NP = (size_t)DIMM*DIMM/4;
    const float4* src; h4* dst; size_t j;
    if (cid < NX)            { src = (const float4*)x;  dst = (h4*)xh;  j = cid; }
    else if (cid < NX+NW)    { src = (const float4*)w;  dst = (h4*)wh;  j = cid - NX; }
    else if (cid < NX+NW+NP) { src = (const float4*)pw; dst = (h4*)pwh; j = cid - NX - NW; }
    else return;
    const float4 v = src[j];
    h4 hh; hh[0]=(_Float16)v.x; hh[1]=(_Float16)v.y; hh[2]=(_Float16)v.z; hh[3]=(_Float16)v.w;
    dst[j] = hh;
}

// ---------------------------------------------------------------- BK=64 staged fp16 GEMM core
template <typename F>
__device__ __forceinline__ void gemm128f2(const _Float16* __restrict__ Ah_g,
                                          const _Float16* __restrict__ Bh_g,
                                          F epi)
{
    __shared__ _Float16 Ah[128][72], Bh[128][72];
    const int t  = threadIdx.x;
    const int wv = t >> 6, lane = t & 63, lo = lane & 15, g = lane >> 4;
    const int gb = g << 3;
    const int wm = (wv >> 1) << 6, wn = (wv & 1) << 6;
    const int bm = blockIdx.y << 7, bn = blockIdx.x << 7;
    f4 acc[4][4] = {};
    const int lr = t >> 1;
    const int lc = (t & 1) << 5;          // 0 or 32
    const int am = bm + lr;
    const bool aok = am < MM;
    const _Float16* arh = Ah_g + (size_t)(aok ? am : 0) * DIMM + lc;
    const _Float16* brh = Bh_g + (size_t)(bn + lr) * DIMM + lc;

    for (int k0 = 0; k0 < DIMM; k0 += 64) {
        h8 a0 = {}, a1 = {}, a2 = {}, a3 = {};
        if (aok) {
            a0 = *(const h8*)(arh + k0);      a1 = *(const h8*)(arh + k0 + 8);
            a2 = *(const h8*)(arh + k0 + 16); a3 = *(const h8*)(arh + k0 + 24);
        }
        const h8 b0 = *(const h8*)(brh + k0),      b1 = *(const h8*)(brh + k0 + 8);
        const h8 b2 = *(const h8*)(brh + k0 + 16), b3 = *(const h8*)(brh + k0 + 24);
        __syncthreads();
        *(h8*)&Ah[lr][lc]    = a0; *(h8*)&Ah[lr][lc+8]  = a1;
        *(h8*)&Ah[lr][lc+16] = a2; *(h8*)&Ah[lr][lc+24] = a3;
        *(h8*)&Bh[lr][lc]    = b0; *(h8*)&Bh[lr][lc+8]  = b1;
        *(h8*)&Bh[lr][lc+16] = b2; *(h8*)&Bh[lr][lc+24] = b3;
        __syncthreads();
        {
            h8 fah[4], fbh[4];
            #pragma unroll
            for (int i = 0; i < 4; ++i) {
                fah[i] = *(const h8*)&Ah[wm + 16*i + lo][gb];
                fbh[i] = *(const h8*)&Bh[wn + 16*i + lo][gb];
            }
            #pragma unroll
            for (int mi = 0; mi < 4; ++mi) {
                #pragma unroll
                for (int ni = 0; ni < 4; ++ni)
                    acc[mi][ni] = __builtin_amdgcn_mfma_f32_16x16x32_f16(fah[mi], fbh[ni], acc[mi][ni], 0, 0, 0);
            }
        }
        {
            h8 fah[4], fbh[4];
            #pragma unroll
            for (int i = 0; i < 4; ++i) {
                fah[i] = *(const h8*)&Ah[wm + 16*i + lo][32 + gb];
                fbh[i] = *(const h8*)&Bh[wn + 16*i + lo][32 + gb];
            }
            #pragma unroll
            for (int mi = 0; mi < 4; ++mi) {
                #pragma unroll
                for (int ni = 0; ni < 4; ++ni)
                    acc[mi][ni] = __builtin_amdgcn_mfma_f32_16x16x32_f16(fah[mi], fbh[ni], acc[mi][ni], 0, 0, 0);
            }
        }
    }
    epi(acc, bm, bn, wm, wn, lo, g);
}

// ---------------------------------------------------------------- QKV GEMM
__global__ __launch_bounds__(256, 3)
void qkv_gemm(const _Float16* __restrict__ xh, const _Float16* __restrict__ wh,
              _Float16* __restrict__ qh, _Float16* __restrict__ kh, _Float16* __restrict__ vh)
{
    gemm128f2(xh, wh, [=](f4 (&acc)[4][4], int bm, int bn, int wm, int wn, int lo, int g) {
        const int three = bn / 768;
        const int cb    = bn - three * 768;
        #pragma unroll
        for (int mi = 0; mi < 4; ++mi) {
            #pragma unroll
            for (int reg = 0; reg < 4; ++reg) {
                const int m = bm + wm + 16*mi + 4*g + reg;
                if (m >= MM) continue;
                const int b_ = m / NNq;
                const int n_ = m - b_ * NNq;
                #pragma unroll
                for (int ni = 0; ni < 4; ++ni) {
                    const int n  = cb + wn + 16*ni + lo;
                    const int hh = n >> 6;
                    const int d  = n & 63;
                    if (three == 0) {
                        // Q scaled 0.125 * log2(e) for the exp2 path
                        qh[((size_t)(b_*NHh + hh)*NPAD + n_)*HD + d] =
                            (_Float16)(acc[mi][ni][reg] * 0.18033688f);
                    } else if (three == 1) {
                        kh[((size_t)(b_*NHh + hh)*NPAD + n_)*HD + d] = (_Float16)acc[mi][ni][reg];
                    } else {
                        vh[((size_t)(b_*NHh + hh)*HD + d)*NPAD + n_] = (_Float16)acc[mi][ni][reg];
                    }
                }
            }
        }
    });
}

// ---------------------------------------------------------------- proj GEMM
__global__ __launch_bounds__(256, 3)
void proj_gemm(const _Float16* __restrict__ aoh, const _Float16* __restrict__ pwh,
               const float* __restrict__ bias, float* __restrict__ out)
{
    gemm128f2(aoh, pwh, [=](f4 (&acc)[4][4], int bm, int bn, int wm, int wn, int lo, int g) {
        #pragma unroll
        for (int ni = 0; ni < 4; ++ni) {
            const int n  = bn + wn + 16*ni + lo;
            const float bb = bias[n];
            #pragma unroll
            for (int mi = 0; mi < 4; ++mi) {
                #pragma unroll
                for (int reg = 0; reg < 4; ++reg) {
                    const int m = bm + wm + 16*mi + 4*g + reg;
                    if (m >= MM) continue;
                    out[(size_t)m*DIMM + n] = acc[mi][ni][reg] + bb;
                }
            }
        }
    });
}

// ---------------------------------------------------------------- fused attention v17 (2 q-tiles/wave, forced 2-wave budget)
__global__ __launch_bounds__(256) __attribute__((amdgpu_waves_per_eu(2, 2)))
void attn_fused(const _Float16* __restrict__ qh,
                const _Float16* __restrict__ kh, const _Float16* __restrict__ vh,
                const float* __restrict__ tkv, const float* __restrict__ tkh,
                const float* __restrict__ tvv, const float* __restrict__ tvh,
                const _Float16* __restrict__ M2g,
                _Float16* __restrict__ aoh)
{
    // LDS 52464 B:
    //   [     0,18432) qrelS fp16 [128][72]
    //   [ 18432,36864) Pt    fp16 [128][72]
    //   [ 36864,52464) TvS   fp32 [60][65]
    //   epilogue: binsS fp32 [128][52] at 0 (26624 B; qrelS + head of Pt dead)
    __shared__ __align__(16) char smem[52464];
    _Float16 (*qrelS)[72] = (_Float16(*)[72])(smem);
    _Float16 (*Pt)[72]    = (_Float16(*)[72])(smem + 18432);
    float    (*TvS)[65]   = (float(*)[65])(smem + 36864);
    float    (*binsS)[52] = (float(*)[52])(smem);

    const int t    = threadIdx.x;
    const int w    = t >> 6;
    const int lane = t & 63;
    const int lo   = lane & 15;
    const int g    = lane >> 4;
    const int gb   = g << 3;

    // ---- XCD-chunked decode: 960 blocks = 8 XCD x 24 heads x 5 q-chunks ----
    const int blk = blockIdx.x;            // 0..959
    const int x8  = blk & 7;
    const int r_  = blk >> 3;              // 0..119
    const int hq  = r_ / 5;                // 0..23
    const int qt  = r_ - hq*5;             // 0..4
    const int bh  = x8 + (hq << 3);        // head 0..191
    const int qt0 = qt * 128;
    const int qrow = 16*w + 4*g;
    const _Float16* qp = qh + (size_t)bh * (NPAD*HD);
    const _Float16* kp = kh + (size_t)bh * (NPAD*HD);
    const _Float16* vp = vh + (size_t)bh * (HD*NPAD);

    for (int e = t; e < 60*64; e += 256) {
        const int r = e >> 6, d = e & 63;
        TvS[r][d] = (r < 30) ? tvv[r*HD + d] : tvh[(r-30)*HD + d];
    }

    // ---- Q fragments for both sub-tiles (pad rows >=577 garbage, discarded) ----
    const h8 a0A = *(const h8*)(qp + (size_t)(qt0 +      16*w + lo)*HD + gb);
    const h8 a1A = *(const h8*)(qp + (size_t)(qt0 +      16*w + lo)*HD + 32 + gb);
    const h8 a0B = *(const h8*)(qp + (size_t)(qt0 + 64 + 16*w + lo)*HD + gb);
    const h8 a1B = *(const h8*)(qp + (size_t)(qt0 + 64 + 16*w + lo)*HD + 32 + gb);

    // ---- qrel for both tiles; table fragments SHARED ----
    {
        f4 qaccA[4] = {f4{0,0,0,0}, f4{0,0,0,0}, f4{0,0,0,0}, f4{0,0,0,0}};
        f4 qaccB[4] = {f4{0,0,0,0}, f4{0,0,0,0}, f4{0,0,0,0}, f4{0,0,0,0}};
        #pragma unroll
        for (int c = 0; c < 4; ++c) {
            const int r16 = 16*c + lo;
            const float* src = (r16 < 30) ? (tkv + r16*HD) : (tkh + (r16-30)*HD);
            h8 tb0 = {}, tb1 = {};
            if (r16 < 60) {
                tb0 = pack8(*(const float4*)(src + gb),      *(const float4*)(src + gb + 4));
                tb1 = pack8(*(const float4*)(src + 32 + gb), *(const float4*)(src + 32 + gb + 4));
            }
            qaccA[c] = __builtin_amdgcn_mfma_f32_16x16x32_f16(a0A, tb0, qaccA[c], 0, 0, 0);
            qaccA[c] = __builtin_amdgcn_mfma_f32_16x16x32_f16(a1A, tb1, qaccA[c], 0, 0, 0);
            qaccB[c] = __builtin_amdgcn_mfma_f32_16x16x32_f16(a0B, tb0, qaccB[c], 0, 0, 0);
            qaccB[c] = __builtin_amdgcn_mfma_f32_16x16x32_f16(a1B, tb1, qaccB[c], 0, 0, 0);
        }
        #pragma unroll
        for (int c = 0; c < 4; ++c) {
            #pragma unroll
            for (int i = 0; i < 4; ++i) {
                qrelS[qrow + i][16*c + lo]      = (_Float16)qaccA[c][i];
                qrelS[64 + qrow + i][16*c + lo] = (_Float16)qaccB[c][i];
            }
        }
    }
    // NO barrier: gathers below read only this wave's own rows.

    int qv_[2][4], qh_[2][4];
    bool q0_[2][4];
    #pragma unroll
    for (int tb = 0; tb < 2; ++tb) {
        #pragma unroll
        for (int i = 0; i < 4; ++i) {
            const int qgl = qt0 + 64*tb + qrow + i;
            q0_[tb][i] = (qgl == 0);
            int qq = qgl - 1; if (qq < 0) qq = 0;
            qv_[tb][i] = qq / 24;
            qh_[tb][i] = qq - qv_[tb][i]*24;
        }
    }

    f4 o_accA [4] = {f4{0,0,0,0}, f4{0,0,0,0}, f4{0,0,0,0}, f4{0,0,0,0}};
    f4 binaccA[4] = {f4{0,0,0,0}, f4{0,0,0,0}, f4{0,0,0,0}, f4{0,0,0,0}};
    f4 o_accB [4] = {f4{0,0,0,0}, f4{0,0,0,0}, f4{0,0,0,0}, f4{0,0,0,0}};
    f4 binaccB[4] = {f4{0,0,0,0}, f4{0,0,0,0}, f4{0,0,0,0}, f4{0,0,0,0}};

    // ================= main loop: 9 full tiles (keys 0..575) =================
    for (int kt0 = 0; kt0 < 576; kt0 += KT) {
        // ---- ONE load batch for both sub-tiles ----
        h8 kb0[4], kb1[4], v0r[4], v1r[4], m20[4], m21[4];
        #pragma unroll
        for (int c = 0; c < 4; ++c) {
            const int key = kt0 + 16*c + lo;
            kb0[c] = *(const h8*)(kp + (size_t)key*HD + gb);
            kb1[c] = *(const h8*)(kp + (size_t)key*HD + 32 + gb);
            const int dd = 16*c + lo;
            v0r[c] = *(const h8*)(vp + (size_t)dd*NPAD + kt0 + gb);
            v1r[c] = *(const h8*)(vp + (size_t)dd*NPAD + kt0 + 32 + gb);
            m20[c] = *(const h8*)(M2g + (size_t)dd*NPAD + kt0 + gb);
            m21[c] = *(const h8*)(M2g + (size_t)dd*NPAD + kt0 + 32 + gb);
        }
        // key decomposition (shared by both sub-tiles)
        int kvc[4], khc[4];
        bool kzc[4];
        #pragma unroll
        for (int c = 0; c < 4; ++c) {
            const int key = kt0 + 16*c + lo;
            int kk = key - 1; if (kk < 0) kk = 0;
            kvc[c] = kk / 24;
            khc[c] = kk - kvc[c]*24;
            kzc[c] = (key == 0);
        }
        // ---- sub-tile A: srel gather -> S -> exp -> Pt rows [0,64) ----
        {
            float srel[4][4];
            #pragma unroll
            for (int c = 0; c < 4; ++c) {
                #pragma unroll
                for (int i = 0; i < 4; ++i) {
                    int colv, colh;
                    if (kzc[c] || q0_[0][i]) { colv = 0; colh = 30; }
                    else {
                        int dv = kvc[c] - qv_[0][i]; dv = min(14, max(-14, dv));
                        int dh = khc[c] - qh_[0][i]; dh = min(14, max(-14, dh));
                        colv = dv + 15; colh = 45 + dh;
                    }
                    srel[c][i] = (float)qrelS[qrow+i][colv] + (float)qrelS[qrow+i][colh];
                }
            }
            __builtin_amdgcn_s_setprio(1);
            f4 Sc[4];
            #pragma unroll
            for (int c = 0; c < 4; ++c) {
                f4 acc = f4{0,0,0,0};
                acc = __builtin_amdgcn_mfma_f32_16x16x32_f16(a0A, kb0[c], acc, 0, 0, 0);
                acc = __builtin_amdgcn_mfma_f32_16x16x32_f16(a1A, kb1[c], acc, 0, 0, 0);
                Sc[c] = acc;
            }
            __builtin_amdgcn_s_setprio(0);
            #pragma unroll
            for (int c = 0; c < 4; ++c) {
                #pragma unroll
                for (int i = 0; i < 4; ++i)
                    Pt[qrow+i][16*c + lo] = (_Float16)exp2f(Sc[c][i] + srel[c][i]);
            }
        }
        // ---- sub-tile B: srel gather -> S -> exp -> Pt rows [64,128) ----
        {
            float srel[4][4];
            #pragma unroll
            for (int c = 0; c < 4; ++c) {
                #pragma unroll
                for (int i = 0; i < 4; ++i) {
                    int colv, colh;
                    if (kzc[c] || q0_[1][i]) { colv = 0; colh = 30; }
                    else {
                        int dv = kvc[c] - qv_[1][i]; dv = min(14, max(-14, dv));
                        int dh = khc[c] - qh_[1][i]; dh = min(14, max(-14, dh));
                        colv = dv + 15; colh = 45 + dh;
                    }
                    srel[c][i] = (float)qrelS[64+qrow+i][colv] + (float)qrelS[64+qrow+i][colh];
                }
            }
            __builtin_amdgcn_s_setprio(1);
            f4 Sc[4];
            #pragma unroll
            for (int c = 0; c < 4; ++c) {
                f4 acc = f4{0,0,0,0};
                acc = __builtin_amdgcn_mfma_f32_16x16x32_f16(a0B, kb0[c], acc, 0, 0, 0);
                acc = __builtin_amdgcn_mfma_f32_16x16x32_f16(a1B, kb1[c], acc, 0, 0, 0);
                Sc[c] = acc;
            }
            __builtin_amdgcn_s_setprio(0);
            #pragma unroll
            for (int c = 0; c < 4; ++c) {
                #pragma unroll
                for (int i = 0; i < 4; ++i)
                    Pt[64+qrow+i][16*c + lo] = (_Float16)exp2f(Sc[c][i] + srel[c][i]);
            }
        }
        // ---- P fragments + bins/PV for both sub-tiles (frags reused) ----
        const h8 p0A = *(const h8*)&Pt[16*w + lo][gb];
        const h8 p1A = *(const h8*)&Pt[16*w + lo][32 + gb];
        const h8 p0B = *(const h8*)&Pt[64 + 16*w + lo][gb];
        const h8 p1B = *(const h8*)&Pt[64 + 16*w + lo][32 + gb];
        __builtin_amdgcn_s_setprio(1);
        #pragma unroll
        for (int c = 0; c < 4; ++c) {
            binaccA[c] = __builtin_amdgcn_mfma_f32_16x16x32_f16(p0A, m20[c], binaccA[c], 0, 0, 0);
            binaccA[c] = __builtin_amdgcn_mfma_f32_16x16x32_f16(p1A, m21[c], binaccA[c], 0, 0, 0);
            binaccB[c] = __builtin_amdgcn_mfma_f32_16x16x32_f16(p0B, m20[c], binaccB[c], 0, 0, 0);
            binaccB[c] = __builtin_amdgcn_mfma_f32_16x16x32_f16(p1B, m21[c], binaccB[c], 0, 0, 0);
        }
        #pragma unroll
        for (int c = 0; c < 4; ++c) {
            o_accA[c] = __builtin_amdgcn_mfma_f32_16x16x32_f16(p0A, v0r[c], o_accA[c], 0, 0, 0);
            o_accA[c] = __builtin_amdgcn_mfma_f32_16x16x32_f16(p1A, v1r[c], o_accA[c], 0, 0, 0);
            o_accB[c] = __builtin_amdgcn_mfma_f32_16x16x32_f16(p0B, v0r[c], o_accB[c], 0, 0, 0);
            o_accB[c] = __builtin_amdgcn_mfma_f32_16x16x32_f16(p1B, v1r[c], o_accB[c], 0, 0, 0);
        }
        __builtin_amdgcn_s_setprio(0);
    }

    // ================= slim last tile: kt0 = 576, 1 valid key =================
    {
        const int kt0 = 576;
        h8 kb0_, kb1_, v0r[4], v1r[4], m20[4], m21[4];
        kb0_ = *(const h8*)(kp + (size_t)(kt0 + lo)*HD + gb);
        kb1_ = *(const h8*)(kp + (size_t)(kt0 + lo)*HD + 32 + gb);
        #pragma unroll
        for (int c = 0; c < 4; ++c) {
            const int dd = 16*c + lo;
            v0r[c] = *(const h8*)(vp + (size_t)dd*NPAD + kt0 + gb);
            v1r[c] = *(const h8*)(vp + (size_t)dd*NPAD + kt0 + 32 + gb);
            m20[c] = *(const h8*)(M2g + (size_t)dd*NPAD + kt0 + gb);
            m21[c] = *(const h8*)(M2g + (size_t)dd*NPAD + kt0 + 32 + gb);
        }
        const int key = kt0 + lo;
        int kk = key - 1;
        const int kv  = kk / 24;
        const int kh2 = kk - kv*24;
        const bool ok = key < NNq;
        // sub-tile A
        {
            float srel0[4];
            #pragma unroll
            for (int i = 0; i < 4; ++i) {
                int colv, colh;
                if (q0_[0][i]) { colv = 0; colh = 30; }
                else {
                    int dv = kv  - qv_[0][i]; dv = min(14, max(-14, dv));
                    int dh = kh2 - qh_[0][i]; dh = min(14, max(-14, dh));
                    colv = dv + 15; colh = 45 + dh;
                }
                srel0[i] = (float)qrelS[qrow+i][colv] + (float)qrelS[qrow+i][colh];
            }
            f4 Sc0 = f4{0,0,0,0};
            Sc0 = __builtin_amdgcn_mfma_f32_16x16x32_f16(a0A, kb0_, Sc0, 0, 0, 0);
            Sc0 = __builtin_amdgcn_mfma_f32_16x16x32_f16(a1A, kb1_, Sc0, 0, 0, 0);
            #pragma unroll
            for (int i = 0; i < 4; ++i)
                Pt[qrow+i][lo] = (_Float16)(ok ? exp2f(Sc0[i] + srel0[i]) : 0.f);
            #pragma unroll
            for (int c = 1; c < 4; ++c)
                #pragma unroll
                for (int i = 0; i < 4; ++i) Pt[qrow+i][16*c + lo] = (_Float16)0.f;
        }
        // sub-tile B
        {
            float srel0[4];
            #pragma unroll
            for (int i = 0; i < 4; ++i) {
                int colv, colh;
                if (q0_[1][i]) { colv = 0; colh = 30; }
                else {
                    int dv = kv  - qv_[1][i]; dv = min(14, max(-14, dv));
                    int dh = kh2 - qh_[1][i]; dh = min(14, max(-14, dh));
                    colv = dv + 15; colh = 45 + dh;
                }
                srel0[i] = (float)qrelS[64+qrow+i][colv] + (float)qrelS[64+qrow+i][colh];
            }
            f4 Sc0 = f4{0,0,0,0};
            Sc0 = __builtin_amdgcn_mfma_f32_16x16x32_f16(a0B, kb0_, Sc0, 0, 0, 0);
            Sc0 = __builtin_amdgcn_mfma_f32_16x16x32_f16(a1B, kb1_, Sc0, 0, 0, 0);
            #pragma unroll
            for (int i = 0; i < 4; ++i)
                Pt[64+qrow+i][lo] = (_Float16)(ok ? exp2f(Sc0[i] + srel0[i]) : 0.f);
            #pragma unroll
            for (int c = 1; c < 4; ++c)
                #pragma unroll
                for (int i = 0; i < 4; ++i) Pt[64+qrow+i][16*c + lo] = (_Float16)0.f;
        }
        const h8 p0A = *(const h8*)&Pt[16*w + lo][gb];
        const h8 p1A = *(const h8*)&Pt[16*w + lo][32 + gb];
        const h8 p0B = *(const h8*)&Pt[64 + 16*w + lo][gb];
        const h8 p1B = *(const h8*)&Pt[64 + 16*w + lo][32 + gb];
        #pragma unroll
        for (int c = 0; c < 4; ++c) {
            binaccA[c] = __builtin_amdgcn_mfma_f32_16x16x32_f16(p0A, m20[c], binaccA[c], 0, 0, 0);
            binaccA[c] = __builtin_amdgcn_mfma_f32_16x16x32_f16(p1A, m21[c], binaccA[c], 0, 0, 0);
            binaccB[c] = __builtin_amdgcn_mfma_f32_16x16x32_f16(p0B, m20[c], binaccB[c], 0, 0, 0);
            binaccB[c] = __builtin_amdgcn_mfma_f32_16x16x32_f16(p1B, m21[c], binaccB[c], 0, 0, 0);
        }
        #pragma unroll
        for (int c = 0; c < 4; ++c) {
            o_accA[c] = __builtin_amdgcn_mfma_f32_16x16x32_f16(p0A, v0r[c], o_accA[c], 0, 0, 0);
            o_accA[c] = __builtin_amdgcn_mfma_f32_16x16x32_f16(p1A, v1r[c], o_accA[c], 0, 0, 0);
            o_accB[c] = __builtin_amdgcn_mfma_f32_16x16x32_f16(p0B, v0r[c], o_accB[c], 0, 0, 0);
            o_accB[c] = __builtin_amdgcn_mfma_f32_16x16x32_f16(p1B, v1r[c], o_accB[c], 0, 0, 0);
        }
    }

    // ---- epilogue ----
    __syncthreads();
    #pragma unroll
    for (int c = 0; c < 4; ++c) {
        const int bc = 16*c + lo;
        if (bc <= 50) {
            #pragma unroll
            for (int i = 0; i < 4; ++i) {
                binsS[qrow+i][bc]      = binaccA[c][i];
                binsS[64+qrow+i][bc]   = binaccB[c][i];
            }
        }
    }
    __syncthreads();

    const int b_ = bh / NHh;
    const int h_ = bh - b_*NHh;
    #pragma unroll
    for (int tb = 0; tb < 2; ++tb) {
        #pragma unroll
        for (int i = 0; i < 4; ++i) {
            const int qr  = 64*tb + qrow + i;
            const int qgl = qt0 + qr;
            if (qgl >= NNq) continue;
            const float l    = binsS[qr][50];
            const float invl = 1.f / l;
            const f4* oa = tb ? o_accB : o_accA;
            float o[4] = {oa[0][i], oa[1][i], oa[2][i], oa[3][i]};
            if (qgl == 0) {
                #pragma unroll
                for (int c = 0; c < 4; ++c) {
                    const int d = 16*c + lo;
                    o[c] += l * (TvS[0][d] + TvS[30][d]);
                }
            } else {
                #pragma unroll
                for (int bin = 0; bin < 24; ++bin) {
                    const float wq = binsS[qr][bin];
                    int dv = bin - qv_[tb][i]; dv = min(14, max(-14, dv));
                    #pragma unroll
                    for (int c = 0; c < 4; ++c) o[c] += wq * TvS[dv+15][16*c + lo];
                }
                {
                    const float wq = binsS[qr][24];
                    #pragma unroll
                    for (int c = 0; c < 4; ++c) o[c] += wq * TvS[0][16*c + lo];
                }
                #pragma unroll
                for (int bin = 0; bin < 24; ++bin) {
                    const float wq = binsS[qr][25+bin];
                    int dh = bin - qh_[tb][i]; dh = min(14, max(-14, dh));
                    #pragma unroll
                    for (int c = 0; c < 4; ++c) o[c] += wq * TvS[45+dh][16*c + lo];
                }
                {
                    const float wq = binsS[qr][49];
                    #pragma unroll
                    for (int c = 0; c < 4; ++c) o[c] += wq * TvS[30][16*c + lo];
                }
            }
            _Float16* dst = aoh + (size_t)(b_*NNq + qgl)*DIMM + h_*HD;
            #pragma unroll
            for (int c = 0; c < 4; ++c) dst[16*c + lo] = (_Float16)(o[c] * invl);
        }
    }
}

// ---------------------------------------------------------------- launcher
extern "C" void kernel_launch(void* const* d_in, const int* in_sizes, int n_in,
                              void* d_out, int out_size, void* d_ws, size_t ws_size,
                              hipStream_t stream)
{
    const float* x      = (const float*)d_in[0];
    const float* qkv_w  = (const float*)d_in[1];
    const float* proj_w = (const float*)d_in[2];
    const float* proj_b = (const float*)d_in[3];
    const float* tkv    = (const float*)d_in[4];
    const float* tkh    = (const float*)d_in[5];
    const float* tvv    = (const float*)d_in[6];
    const float* tvh    = (const float*)d_in[7];
    float* out = (float*)d_out;
    float* ws  = (float*)d_ws;

    const size_t KV = (size_t)BB * NHh * NPAD * HD;      // 7,864,320 halves per tensor
    _Float16* qh  = (_Float16*)ws;
    _Float16* kh  = qh + KV;
    _Float16* vh  = kh + KV;
    _Float16* aoh = vh + KV;                              // MM*DIMM halves
    _Float16* M2g = aoh + (size_t)MM*DIMM;
    _Float16* xh  = M2g + NPAD*64;
    _Float16* wh  = xh + (size_t)MM*DIMM;
    _Float16* pwh = wh + (size_t)NW3*DIMM;

    dim3 b256(256, 1, 1);
    // 40960 (M2) + 786432 (vpad) + 2362368 (converts) = 3189760 = 12460 * 256
    init_all<<<12460, b256, 0, stream>>>(x, qkv_w, proj_w, M2g, vh, xh, wh, pwh);

    dim3 g1(NW3/128, (MM + 127)/128, 1);                 // 18 x 73
    qkv_gemm<<<g1, b256, 0, stream>>>(xh, wh, qh, kh, vh);

    // 192 heads x 5 q-chunks of 128 rows, XCD-chunked
    attn_fused<<<dim3(960,1,1), b256, 0, stream>>>(qh, kh, vh, tkv, tkh, tvv, tvh, M2g, aoh);

    dim3 g3(DIMM/128, (MM + 127)/128, 1);                // 6 x 73
    proj_gemm<<<g3, b256, 0, stream>>>(aoh, pwh, proj_b, out);
}